// Round 11
// baseline (190.617 us; speedup 1.0000x reference)
//
#include <hip/hip_runtime.h>

typedef __bf16 bf16x8 __attribute__((ext_vector_type(8)));
typedef float f32x4 __attribute__((ext_vector_type(4)));
typedef unsigned short ushort_t;
typedef unsigned int uint_t;

constexpr int S = 4096, DMODEL = 1024, NH = 16, HD = 64;
// softmax scale folded with log2(e): scores come out of QK^T already in log2 domain
#define QSCALE 0.18033688011112042f  // 0.125 * log2(e)

#if __has_builtin(__builtin_amdgcn_exp2f)
#define EXP2(x) __builtin_amdgcn_exp2f(x)
#else
#define EXP2(x) exp2f(x)
#endif

__device__ inline ushort_t f2bf(float f) {
  uint_t u = __builtin_bit_cast(uint_t, f);
  u = u + 0x7FFFu + ((u >> 16) & 1u);  // round-to-nearest-even
  return (ushort_t)(u >> 16);
}

__device__ inline ushort_t f2bf_hw(float f) {
  __bf16 h = (__bf16)f;  // v_cvt RNE on gfx950
  return __builtin_bit_cast(ushort_t, h);
}

__device__ inline void gl2lds16(const ushort_t* g, ushort_t* l) {
  __builtin_amdgcn_global_load_lds(
      (const __attribute__((address_space(1))) unsigned int*)g,
      (__attribute__((address_space(3))) unsigned int*)l, 16, 0, 0);
}

// ---------------- fp32 -> bf16 conversion ----------------
__global__ __launch_bounds__(256) void cvt_f32_bf16(const float* __restrict__ in,
                                                    ushort_t* __restrict__ out, int n4) {
  int i = blockIdx.x * 256 + threadIdx.x;
  if (i >= n4) return;
  float4 f = reinterpret_cast<const float4*>(in)[i];
  ushort4 o;
  o.x = f2bf(f.x); o.y = f2bf(f.y); o.z = f2bf(f.z); o.w = f2bf(f.w);
  reinterpret_cast<ushort4*>(out)[i] = o;
}

// ---------------- GEMM: C[M][N] = A[M][K] * B[N][K]^T (both row-major [rows][K], bf16) ----
// EPI 0: write fp32 C row-major (ldc=N).  EPI 1: scatter qkv -> qb[h][s][d] (PRE-SCALED by
// QSCALE so attention scores land in log2 domain), kb[h][s][d], vtb[h][d][s] (bf16)
template <int EPI>
__global__ __launch_bounds__(256) void gemm_bt(const ushort_t* __restrict__ A,
                                               const ushort_t* __restrict__ B,
                                               int M, int N, int K,
                                               float* __restrict__ Cf,
                                               ushort_t* __restrict__ qb,
                                               ushort_t* __restrict__ kb,
                                               ushort_t* __restrict__ vtb) {
  __shared__ ushort_t sA[128 * 64];
  __shared__ ushort_t sB[128 * 64];
  const int t = threadIdx.x;
  const int lane = t & 63, w = t >> 6;
  const int wr = w >> 1, wc = w & 1;
  const int rA0 = blockIdx.y * 128, rB0 = blockIdx.x * 128;

  f32x4 acc[4][4];
#pragma unroll
  for (int m = 0; m < 4; ++m)
#pragma unroll
    for (int n = 0; n < 4; ++n) acc[m][n] = (f32x4){0.f, 0.f, 0.f, 0.f};

  const int srow = t >> 3;        // 0..31 staging row within 32-row chunk
  const int scol = (t & 7) * 8;   // staging col (elems)
  const int ldsbase = w * 512;    // wave-uniform lds base (elems) within 2048-elem chunk

  for (int k0 = 0; k0 < K; k0 += 64) {
#pragma unroll
    for (int i = 0; i < 4; ++i) {
      int r = i * 32 + srow;
      int kc = scol ^ ((r & 7) << 3);  // pre-swizzled global source (T2, both-sides rule)
      gl2lds16(&A[(size_t)(rA0 + r) * K + k0 + kc], &sA[i * 2048 + ldsbase]);
    }
#pragma unroll
    for (int i = 0; i < 4; ++i) {
      int r = i * 32 + srow;
      int kc = scol ^ ((r & 7) << 3);
      gl2lds16(&B[(size_t)(rB0 + r) * K + k0 + kc], &sB[i * 2048 + ldsbase]);
    }
    __syncthreads();
#pragma unroll
    for (int ks = 0; ks < 2; ++ks) {
      const int kk = ks * 32 + (lane >> 4) * 8;
      bf16x8 af[4], bfr[4];
#pragma unroll
      for (int m = 0; m < 4; ++m) {
        int row = wr * 64 + m * 16 + (lane & 15);
        af[m] = *(const bf16x8*)&sA[row * 64 + (kk ^ ((row & 7) << 3))];
      }
#pragma unroll
      for (int n = 0; n < 4; ++n) {
        int row = wc * 64 + n * 16 + (lane & 15);
        bfr[n] = *(const bf16x8*)&sB[row * 64 + (kk ^ ((row & 7) << 3))];
      }
#pragma unroll
      for (int m = 0; m < 4; ++m)
#pragma unroll
        for (int n = 0; n < 4; ++n)
          acc[m][n] = __builtin_amdgcn_mfma_f32_16x16x32_bf16(af[m], bfr[n], acc[m][n], 0, 0, 0);
    }
    __syncthreads();
  }

#pragma unroll
  for (int m = 0; m < 4; ++m)
#pragma unroll
    for (int n = 0; n < 4; ++n)
#pragma unroll
      for (int r = 0; r < 4; ++r) {
        int row = rA0 + wr * 64 + m * 16 + (lane >> 4) * 4 + r;
        int col = rB0 + wc * 64 + n * 16 + (lane & 15);
        float v = acc[m][n][r];
        if constexpr (EPI == 0) {
          Cf[(size_t)row * N + col] = v;
        } else {
          int t3 = col >> 10, h = (col >> 6) & 15, d = col & 63;
          if (t3 == 0)      qb[((size_t)h * S + row) * HD + d] = f2bf_hw(v * QSCALE);
          else if (t3 == 1) kb[((size_t)h * S + row) * HD + d] = f2bf_hw(v);
          else              vtb[((size_t)h * HD + d) * S + row] = f2bf_hw(v);
        }
      }
}

// ---------------- GEMM BN=64 variant (fp32 out): for O-proj, doubles block count --------
__global__ __launch_bounds__(256) void gemm_bt_n64(const ushort_t* __restrict__ A,
                                                   const ushort_t* __restrict__ B,
                                                   int M, int N, int K,
                                                   float* __restrict__ Cf) {
  __shared__ ushort_t sA[128 * 64];
  __shared__ ushort_t sB[64 * 64];
  const int t = threadIdx.x;
  const int lane = t & 63, w = t >> 6;
  const int wr = w >> 1, wc = w & 1;  // wave tile: 64 M x 32 N
  const int rA0 = blockIdx.y * 128, rB0 = blockIdx.x * 64;

  f32x4 acc[4][2];
#pragma unroll
  for (int m = 0; m < 4; ++m)
#pragma unroll
    for (int n = 0; n < 2; ++n) acc[m][n] = (f32x4){0.f, 0.f, 0.f, 0.f};

  const int srow = t >> 3;
  const int scol = (t & 7) * 8;
  const int ldsbase = w * 512;

  for (int k0 = 0; k0 < K; k0 += 64) {
#pragma unroll
    for (int i = 0; i < 4; ++i) {
      int r = i * 32 + srow;
      int kc = scol ^ ((r & 7) << 3);
      gl2lds16(&A[(size_t)(rA0 + r) * K + k0 + kc], &sA[i * 2048 + ldsbase]);
    }
#pragma unroll
    for (int i = 0; i < 2; ++i) {
      int r = i * 32 + srow;
      int kc = scol ^ ((r & 7) << 3);
      gl2lds16(&B[(size_t)(rB0 + r) * K + k0 + kc], &sB[i * 2048 + ldsbase]);
    }
    __syncthreads();
#pragma unroll
    for (int ks = 0; ks < 2; ++ks) {
      const int kk = ks * 32 + (lane >> 4) * 8;
      bf16x8 af[4], bfr[2];
#pragma unroll
      for (int m = 0; m < 4; ++m) {
        int row = wr * 64 + m * 16 + (lane & 15);
        af[m] = *(const bf16x8*)&sA[row * 64 + (kk ^ ((row & 7) << 3))];
      }
#pragma unroll
      for (int n = 0; n < 2; ++n) {
        int row = wc * 32 + n * 16 + (lane & 15);
        bfr[n] = *(const bf16x8*)&sB[row * 64 + (kk ^ ((row & 7) << 3))];
      }
#pragma unroll
      for (int m = 0; m < 4; ++m)
#pragma unroll
        for (int n = 0; n < 2; ++n)
          acc[m][n] = __builtin_amdgcn_mfma_f32_16x16x32_bf16(af[m], bfr[n], acc[m][n], 0, 0, 0);
    }
    __syncthreads();
  }

#pragma unroll
  for (int m = 0; m < 4; ++m)
#pragma unroll
    for (int n = 0; n < 2; ++n)
#pragma unroll
      for (int r = 0; r < 4; ++r) {
        int row = rA0 + wr * 64 + m * 16 + (lane >> 4) * 4 + r;
        int col = rB0 + wc * 32 + n * 16 + (lane & 15);
        Cf[(size_t)row * N + col] = acc[m][n][r];
      }
}

// ---------------- flash attention: QBLK=128, 4 waves x 32q, shared-fragment MFMA ---------
// Each wave owns 32 q rows (two 16-q groups). K/V fragments (MFMA B-operands) are
// IDENTICAL for both groups -> read once, feed two independent MFMA chains: per-16q LDS
// drops from 18 to 10 ds_read_b128 (-44%) and per-stage MFMA doubles (ILP instead of
// occupancy). 3-buf counted-vmcnt pipeline (R6), T1 XCD swizzle (R9), T5 setprio,
// fixed-reference softmax (R4/R5): p = 2^s, no max tracking.
__global__ __launch_bounds__(256) void attn_fwd(const ushort_t* __restrict__ qb,
                                                const ushort_t* __restrict__ kb,
                                                const ushort_t* __restrict__ vtb,
                                                ushort_t* __restrict__ aob) {
  __shared__ ushort_t sK[3][64 * 64];  // [buf][kv][d]
  __shared__ ushort_t sV[3][64 * 64];  // [buf][d][kv]  (V transposed)
  __shared__ ushort_t sP[4][32 * 64];  // per-wave P tile [q][kv]
  const int t = threadIdx.x, lane = t & 63, w = t >> 6;  // 4 waves
  // XCD swizzle: grid 512 (1-D), 8 XCDs, 64 blocks/XCD -> 2 heads per XCD
  const int f = blockIdx.x;
  const int sidx = (f & 7) * 64 + (f >> 3);  // bijective (512 % 8 == 0)
  const int h = sidx >> 5;
  const int q0 = (sidx & 31) * 128;
  const ushort_t* qh = qb + (size_t)h * S * HD;
  const ushort_t* kh = kb + (size_t)h * S * HD;
  const ushort_t* vh = vtb + (size_t)h * HD * S;

  const int l15 = lane & 15, g = lane >> 4;
  const int kk0 = g * 8;

  // Q fragments: wave owns rows [q0 + w*32, +32); two 16-q groups
  bf16x8 qf[2][2];  // [qg][ks]
#pragma unroll
  for (int qg = 0; qg < 2; ++qg) {
    const ushort_t* p = &qh[(size_t)(q0 + w * 32 + qg * 16 + l15) * HD + kk0];
    qf[qg][0] = *(const bf16x8*)p;
    qf[qg][1] = *(const bf16x8*)(p + 32);
  }
  f32x4 acc[2][4];
#pragma unroll
  for (int qg = 0; qg < 2; ++qg)
#pragma unroll
    for (int n = 0; n < 4; ++n) acc[qg][n] = (f32x4){0.f, 0.f, 0.f, 0.f};
  float lsum[2][4] = {{0.f, 0.f, 0.f, 0.f}, {0.f, 0.f, 0.f, 0.f}};

  // staging: 256 threads, 2 passes each for K and V (4 gl2lds per thread per tile)
  const int srow = t >> 3;                  // 0..31
  const int scol = (t & 7) * 8;             // col (elems)
  const int kc = scol ^ ((srow & 7) << 3);  // pre-swizzled global source (r&7 == srow&7)
  const int ldsbase = w * 512;              // wave-uniform base within 2048-elem chunk

  auto stage = [&](int buf, int kv0) {
#pragma unroll
    for (int i = 0; i < 2; ++i) {
      int r = i * 32 + srow;
      gl2lds16(&kh[(size_t)(kv0 + r) * HD + kc], &sK[buf][i * 2048 + ldsbase]);
    }
#pragma unroll
    for (int i = 0; i < 2; ++i) {
      int r = i * 32 + srow;
      gl2lds16(&vh[(size_t)r * S + kv0 + kc], &sV[buf][i * 2048 + ldsbase]);
    }
  };

  constexpr int NT = S / 64;
  stage(0, 0);
  stage(1, 64);

  for (int ti = 0; ti < NT; ++ti) {
    const int buf = ti % 3;
    // stage ti+2; counted vmcnt: own tile-ti loads (4) done when the 8 newer remain
    if (ti + 2 < NT) {
      stage((ti + 2) % 3, (ti + 2) * 64);
      asm volatile("s_waitcnt vmcnt(8)" ::: "memory");
    } else if (ti + 1 < NT) {
      asm volatile("s_waitcnt vmcnt(4)" ::: "memory");
    } else {
      asm volatile("s_waitcnt vmcnt(0)" ::: "memory");
    }
    __builtin_amdgcn_sched_barrier(0);
    __builtin_amdgcn_s_barrier();  // A: tile-ti K/V visible to all waves

    const ushort_t* Kb = &sK[buf][0];
    const ushort_t* Vb = &sV[buf][0];

    // S-tiles = Q K^T for both q-groups; kf read ONCE per (nt,ks), 2 MFMA each
    f32x4 sc[2][4];
    __builtin_amdgcn_s_setprio(1);
#pragma unroll
    for (int nt = 0; nt < 4; ++nt) {
      int row = nt * 16 + l15;
      const int rsw = (row & 7) << 3;
      bf16x8 kf0 = *(const bf16x8*)&Kb[row * 64 + ((0 * 32 + kk0) ^ rsw)];
      bf16x8 kf1 = *(const bf16x8*)&Kb[row * 64 + ((1 * 32 + kk0) ^ rsw)];
#pragma unroll
      for (int qg = 0; qg < 2; ++qg) {
        sc[qg][nt] = __builtin_amdgcn_mfma_f32_16x16x32_bf16(qf[qg][0], kf0,
                       (f32x4){0.f, 0.f, 0.f, 0.f}, 0, 0, 0);
        sc[qg][nt] = __builtin_amdgcn_mfma_f32_16x16x32_bf16(qf[qg][1], kf1, sc[qg][nt], 0, 0, 0);
      }
    }
    __builtin_amdgcn_s_setprio(0);

    // fixed-reference softmax in-place: sc <- 2^sc
#pragma unroll
    for (int qg = 0; qg < 2; ++qg)
#pragma unroll
      for (int r = 0; r < 4; ++r) {
        float ps = 0.f;
#pragma unroll
        for (int nt = 0; nt < 4; ++nt) {
          float pv = EXP2(sc[qg][nt][r]);
          sc[qg][nt][r] = pv;
          ps += pv;
        }
        lsum[qg][r] += ps;
      }
    // P -> per-wave LDS (swizzled), rows 0..31
    const int prow_base = g * 4;
#pragma unroll
    for (int qg = 0; qg < 2; ++qg)
#pragma unroll
      for (int nt = 0; nt < 4; ++nt) {
        int col = nt * 16 + l15;
#pragma unroll
        for (int r = 0; r < 4; ++r) {
          int row = qg * 16 + prow_base + r;
          sP[w][row * 64 + (col ^ ((row & 7) << 3))] = f2bf_hw(sc[qg][nt][r]);
        }
      }
    bf16x8 pf[2][2];  // [qg][ks]
#pragma unroll
    for (int qg = 0; qg < 2; ++qg) {
      int row = qg * 16 + l15;
      const int rsw = (row & 7) << 3;
#pragma unroll
      for (int ks = 0; ks < 2; ++ks)
        pf[qg][ks] = *(const bf16x8*)&sP[w][row * 64 + ((ks * 32 + kk0) ^ rsw)];
    }
    // O += P V; vf read ONCE per (nt,ks), 2 MFMA each
    __builtin_amdgcn_s_setprio(1);
#pragma unroll
    for (int nt = 0; nt < 4; ++nt) {
      int row = nt * 16 + l15;
      const int rsw = (row & 7) << 3;
      bf16x8 vf0 = *(const bf16x8*)&Vb[row * 64 + ((0 * 32 + kk0) ^ rsw)];
      bf16x8 vf1 = *(const bf16x8*)&Vb[row * 64 + ((1 * 32 + kk0) ^ rsw)];
#pragma unroll
      for (int qg = 0; qg < 2; ++qg) {
        acc[qg][nt] = __builtin_amdgcn_mfma_f32_16x16x32_bf16(pf[qg][0], vf0, acc[qg][nt], 0, 0, 0);
        acc[qg][nt] = __builtin_amdgcn_mfma_f32_16x16x32_bf16(pf[qg][1], vf1, acc[qg][nt], 0, 0, 0);
      }
    }
    __builtin_amdgcn_s_setprio(0);
    __builtin_amdgcn_s_barrier();  // B: all reads of buf done before next overwrite
  }
  // epilogue: reduce per-lane partial sums across the 16-lane row group, write out
#pragma unroll
  for (int qg = 0; qg < 2; ++qg) {
    float linv[4];
#pragma unroll
    for (int r = 0; r < 4; ++r) {
      float l = lsum[qg][r];
      l += __shfl_xor(l, 1);
      l += __shfl_xor(l, 2);
      l += __shfl_xor(l, 4);
      l += __shfl_xor(l, 8);
      linv[r] = 1.0f / l;
    }
#pragma unroll
    for (int nt = 0; nt < 4; ++nt)
#pragma unroll
      for (int r = 0; r < 4; ++r) {
        int row = q0 + w * 32 + qg * 16 + g * 4 + r;
        int col = h * HD + nt * 16 + l15;
        aob[(size_t)row * DMODEL + col] = f2bf_hw(acc[qg][nt][r] * linv[r]);
      }
  }
}

extern "C" void kernel_launch(void* const* d_in, const int* in_sizes, int n_in,
                              void* d_out, int out_size, void* d_ws, size_t ws_size,
                              hipStream_t stream) {
  const float* x = (const float*)d_in[0];
  const float* wqkv = (const float*)d_in[1];
  const float* wo = (const float*)d_in[2];
  float* out = (float*)d_out;
  char* ws = (char*)d_ws;
  const size_t MB = 1024ull * 1024ull;
  ushort_t* xb  = (ushort_t*)(ws);             // x bf16          [4096][1024]  8MB
  ushort_t* wqb = (ushort_t*)(ws + 8 * MB);    // w_qkv bf16      [3072][1024]  6MB
  ushort_t* wob = (ushort_t*)(ws + 14 * MB);   // w_o bf16        [1024][1024]  2MB
  ushort_t* qb  = (ushort_t*)(ws + 16 * MB);   // Q  [16][4096][64]             8MB
  ushort_t* kb  = (ushort_t*)(ws + 24 * MB);   // K  [16][4096][64]             8MB
  ushort_t* vtb = (ushort_t*)(ws + 32 * MB);   // V^T [16][64][4096]            8MB
  ushort_t* aob = (ushort_t*)(ws + 40 * MB);   // attn out bf16 [4096][1024]    8MB

  cvt_f32_bf16<<<(S * DMODEL / 4 + 255) / 256, 256, 0, stream>>>(x, xb, S * DMODEL / 4);
  cvt_f32_bf16<<<(3 * DMODEL * DMODEL / 4 + 255) / 256, 256, 0, stream>>>(wqkv, wqb, 3 * DMODEL * DMODEL / 4);
  cvt_f32_bf16<<<(DMODEL * DMODEL / 4 + 255) / 256, 256, 0, stream>>>(wo, wob, DMODEL * DMODEL / 4);

  dim3 g1(3 * DMODEL / 128, S / 128);
  gemm_bt<1><<<g1, 256, 0, stream>>>(xb, wqb, S, 3 * DMODEL, DMODEL, nullptr, qb, kb, vtb);

  attn_fwd<<<dim3(512), 256, 0, stream>>>(qb, kb, vtb, aob);

  dim3 g2(DMODEL / 64, S / 128);
  gemm_bt_n64<<<g2, 256, 0, stream>>>(aob, wob, S, DMODEL, DMODEL, out);
}

// Round 12
// 173.099 us; speedup vs baseline: 1.1012x; 1.1012x over previous
//
#include <hip/hip_runtime.h>

typedef __bf16 bf16x8 __attribute__((ext_vector_type(8)));
typedef float f32x4 __attribute__((ext_vector_type(4)));
typedef unsigned short ushort_t;
typedef unsigned int uint_t;

constexpr int S = 4096, DMODEL = 1024, NH = 16, HD = 64;
// softmax scale folded with log2(e): scores come out of QK^T already in log2 domain
#define QSCALE 0.18033688011112042f  // 0.125 * log2(e)

#if __has_builtin(__builtin_amdgcn_exp2f)
#define EXP2(x) __builtin_amdgcn_exp2f(x)
#else
#define EXP2(x) exp2f(x)
#endif

__device__ inline ushort_t f2bf(float f) {
  uint_t u = __builtin_bit_cast(uint_t, f);
  u = u + 0x7FFFu + ((u >> 16) & 1u);  // round-to-nearest-even
  return (ushort_t)(u >> 16);
}

__device__ inline ushort_t f2bf_hw(float f) {
  __bf16 h = (__bf16)f;  // v_cvt RNE on gfx950
  return __builtin_bit_cast(ushort_t, h);
}

__device__ inline void gl2lds16(const ushort_t* g, ushort_t* l) {
  __builtin_amdgcn_global_load_lds(
      (const __attribute__((address_space(1))) unsigned int*)g,
      (__attribute__((address_space(3))) unsigned int*)l, 16, 0, 0);
}

// ---------------- fp32 -> bf16 conversion ----------------
__global__ __launch_bounds__(256) void cvt_f32_bf16(const float* __restrict__ in,
                                                    ushort_t* __restrict__ out, int n4) {
  int i = blockIdx.x * 256 + threadIdx.x;
  if (i >= n4) return;
  float4 f = reinterpret_cast<const float4*>(in)[i];
  ushort4 o;
  o.x = f2bf(f.x); o.y = f2bf(f.y); o.z = f2bf(f.z); o.w = f2bf(f.w);
  reinterpret_cast<ushort4*>(out)[i] = o;
}

// ---------------- GEMM: C[M][N] = A[M][K] * B[N][K]^T (both row-major [rows][K], bf16) ----
// T1 XCD swizzle: contiguous nwg/8 chunk of tiles per XCD (nwg % 8 == 0).
// EPI 0: write fp32 C row-major (ldc=N).  EPI 1: scatter qkv -> qb[h][s][d] (PRE-SCALED by
// QSCALE so attention scores land in log2 domain), kb[h][s][d], vtb[h][d][s] (bf16)
template <int EPI>
__global__ __launch_bounds__(256) void gemm_bt(const ushort_t* __restrict__ A,
                                               const ushort_t* __restrict__ B,
                                               int M, int N, int K,
                                               float* __restrict__ Cf,
                                               ushort_t* __restrict__ qb,
                                               ushort_t* __restrict__ kb,
                                               ushort_t* __restrict__ vtb) {
  __shared__ ushort_t sA[128 * 64];
  __shared__ ushort_t sB[128 * 64];
  const int t = threadIdx.x;
  const int lane = t & 63, w = t >> 6;
  const int wr = w >> 1, wc = w & 1;
  // XCD-aware block swizzle (bijective since nwg % 8 == 0)
  const int lin = blockIdx.y * gridDim.x + blockIdx.x;
  const int cpx = (gridDim.x * gridDim.y) >> 3;
  const int swz = (lin & 7) * cpx + (lin >> 3);
  const int rA0 = (swz / gridDim.x) * 128, rB0 = (swz % gridDim.x) * 128;

  f32x4 acc[4][4];
#pragma unroll
  for (int m = 0; m < 4; ++m)
#pragma unroll
    for (int n = 0; n < 4; ++n) acc[m][n] = (f32x4){0.f, 0.f, 0.f, 0.f};

  const int srow = t >> 3;        // 0..31 staging row within 32-row chunk
  const int scol = (t & 7) * 8;   // staging col (elems)
  const int ldsbase = w * 512;    // wave-uniform lds base (elems) within 2048-elem chunk

  for (int k0 = 0; k0 < K; k0 += 64) {
#pragma unroll
    for (int i = 0; i < 4; ++i) {
      int r = i * 32 + srow;
      int kc = scol ^ ((r & 7) << 3);  // pre-swizzled global source (T2, both-sides rule)
      gl2lds16(&A[(size_t)(rA0 + r) * K + k0 + kc], &sA[i * 2048 + ldsbase]);
    }
#pragma unroll
    for (int i = 0; i < 4; ++i) {
      int r = i * 32 + srow;
      int kc = scol ^ ((r & 7) << 3);
      gl2lds16(&B[(size_t)(rB0 + r) * K + k0 + kc], &sB[i * 2048 + ldsbase]);
    }
    __syncthreads();
#pragma unroll
    for (int ks = 0; ks < 2; ++ks) {
      const int kk = ks * 32 + (lane >> 4) * 8;
      bf16x8 af[4], bfr[4];
#pragma unroll
      for (int m = 0; m < 4; ++m) {
        int row = wr * 64 + m * 16 + (lane & 15);
        af[m] = *(const bf16x8*)&sA[row * 64 + (kk ^ ((row & 7) << 3))];
      }
#pragma unroll
      for (int n = 0; n < 4; ++n) {
        int row = wc * 64 + n * 16 + (lane & 15);
        bfr[n] = *(const bf16x8*)&sB[row * 64 + (kk ^ ((row & 7) << 3))];
      }
#pragma unroll
      for (int m = 0; m < 4; ++m)
#pragma unroll
        for (int n = 0; n < 4; ++n)
          acc[m][n] = __builtin_amdgcn_mfma_f32_16x16x32_bf16(af[m], bfr[n], acc[m][n], 0, 0, 0);
    }
    __syncthreads();
  }

#pragma unroll
  for (int m = 0; m < 4; ++m)
#pragma unroll
    for (int n = 0; n < 4; ++n)
#pragma unroll
      for (int r = 0; r < 4; ++r) {
        int row = rA0 + wr * 64 + m * 16 + (lane >> 4) * 4 + r;
        int col = rB0 + wc * 64 + n * 16 + (lane & 15);
        float v = acc[m][n][r];
        if constexpr (EPI == 0) {
          Cf[(size_t)row * N + col] = v;
        } else {
          int t3 = col >> 10, h = (col >> 6) & 15, d = col & 63;
          if (t3 == 0)      qb[((size_t)h * S + row) * HD + d] = f2bf_hw(v * QSCALE);
          else if (t3 == 1) kb[((size_t)h * S + row) * HD + d] = f2bf_hw(v);
          else              vtb[((size_t)h * HD + d) * S + row] = f2bf_hw(v);
        }
      }
}

// ---------------- GEMM BN=64 variant (fp32 out): for O-proj, doubles block count --------
__global__ __launch_bounds__(256) void gemm_bt_n64(const ushort_t* __restrict__ A,
                                                   const ushort_t* __restrict__ B,
                                                   int M, int N, int K,
                                                   float* __restrict__ Cf) {
  __shared__ ushort_t sA[128 * 64];
  __shared__ ushort_t sB[64 * 64];
  const int t = threadIdx.x;
  const int lane = t & 63, w = t >> 6;
  const int wr = w >> 1, wc = w & 1;  // wave tile: 64 M x 32 N
  const int lin = blockIdx.y * gridDim.x + blockIdx.x;
  const int cpx = (gridDim.x * gridDim.y) >> 3;
  const int swz = (lin & 7) * cpx + (lin >> 3);
  const int rA0 = (swz / gridDim.x) * 128, rB0 = (swz % gridDim.x) * 64;

  f32x4 acc[4][2];
#pragma unroll
  for (int m = 0; m < 4; ++m)
#pragma unroll
    for (int n = 0; n < 2; ++n) acc[m][n] = (f32x4){0.f, 0.f, 0.f, 0.f};

  const int srow = t >> 3;
  const int scol = (t & 7) * 8;
  const int ldsbase = w * 512;

  for (int k0 = 0; k0 < K; k0 += 64) {
#pragma unroll
    for (int i = 0; i < 4; ++i) {
      int r = i * 32 + srow;
      int kc = scol ^ ((r & 7) << 3);
      gl2lds16(&A[(size_t)(rA0 + r) * K + k0 + kc], &sA[i * 2048 + ldsbase]);
    }
#pragma unroll
    for (int i = 0; i < 2; ++i) {
      int r = i * 32 + srow;
      int kc = scol ^ ((r & 7) << 3);
      gl2lds16(&B[(size_t)(rB0 + r) * K + k0 + kc], &sB[i * 2048 + ldsbase]);
    }
    __syncthreads();
#pragma unroll
    for (int ks = 0; ks < 2; ++ks) {
      const int kk = ks * 32 + (lane >> 4) * 8;
      bf16x8 af[4], bfr[2];
#pragma unroll
      for (int m = 0; m < 4; ++m) {
        int row = wr * 64 + m * 16 + (lane & 15);
        af[m] = *(const bf16x8*)&sA[row * 64 + (kk ^ ((row & 7) << 3))];
      }
#pragma unroll
      for (int n = 0; n < 2; ++n) {
        int row = wc * 32 + n * 16 + (lane & 15);
        bfr[n] = *(const bf16x8*)&sB[row * 64 + (kk ^ ((row & 7) << 3))];
      }
#pragma unroll
      for (int m = 0; m < 4; ++m)
#pragma unroll
        for (int n = 0; n < 2; ++n)
          acc[m][n] = __builtin_amdgcn_mfma_f32_16x16x32_bf16(af[m], bfr[n], acc[m][n], 0, 0, 0);
    }
    __syncthreads();
  }

#pragma unroll
  for (int m = 0; m < 4; ++m)
#pragma unroll
    for (int n = 0; n < 2; ++n)
#pragma unroll
      for (int r = 0; r < 4; ++r) {
        int row = rA0 + wr * 64 + m * 16 + (lane >> 4) * 4 + r;
        int col = rB0 + wc * 32 + n * 16 + (lane & 15);
        Cf[(size_t)row * N + col] = acc[m][n][r];
      }
}

// ---------------- flash attention: QBLK=128, 8 waves, 3-buf, SINGLE barrier per tile -----
// Iteration: vmcnt(2) [own tile-ti K/V done; stage(ti+1) stays in flight] -> barrier
// [cross-wave: everyone's tile-ti visible AND everyone finished reading buf[(ti+2)%3] at
// iter ti-1 (their PV lgkm drained before MFMA use, MFMA before barrier arrival)] ->
// stage(ti+2) [safe: that buf has no readers now] -> compute. Half the barriers of R6.
// T1 XCD swizzle (R9: 2 heads/XCD, K/V L2-resident). Fixed-reference softmax (R4/R5).
__global__ __launch_bounds__(512) void attn_fwd(const ushort_t* __restrict__ qb,
                                                const ushort_t* __restrict__ kb,
                                                const ushort_t* __restrict__ vtb,
                                                ushort_t* __restrict__ aob) {
  __shared__ ushort_t sK[3][64 * 64];
  __shared__ ushort_t sV[3][64 * 64];  // V transposed: [d][kv]
  __shared__ ushort_t sP[8][16 * 64];  // per-wave P tile
  const int t = threadIdx.x, lane = t & 63, w = t >> 6;  // 8 waves
  // XCD swizzle: grid 512 (1-D), 8 XCDs, 64 blocks/XCD -> 2 heads per XCD
  const int f = blockIdx.x;
  const int sidx = (f & 7) * 64 + (f >> 3);  // bijective (512 % 8 == 0)
  const int h = sidx >> 5;
  const int q0 = (sidx & 31) * 128;
  const ushort_t* qh = qb + (size_t)h * S * HD;
  const ushort_t* kh = kb + (size_t)h * S * HD;
  const ushort_t* vh = vtb + (size_t)h * HD * S;

  // Q fragments in registers: wave owns 16 q rows (already scaled by 0.125*log2e)
  bf16x8 qf[2];
  {
    int qr = q0 + w * 16 + (lane & 15);
    const ushort_t* p = &qh[(size_t)qr * HD + (lane >> 4) * 8];
    qf[0] = *(const bf16x8*)p;
    qf[1] = *(const bf16x8*)(p + 32);
  }
  f32x4 acc[4];
#pragma unroll
  for (int n = 0; n < 4; ++n) acc[n] = (f32x4){0.f, 0.f, 0.f, 0.f};
  float lsum[4] = {0.f, 0.f, 0.f, 0.f};  // per-lane partial denominators

  // staging: 512 threads cover one 64x64 tile in a single pass (1 load each for K and V)
  const int srow = t >> 3;                  // 0..63
  const int scol = (t & 7) * 8;             // col (elems)
  const int kc = scol ^ ((srow & 7) << 3);  // pre-swizzled global source
  const int ldsbase = w * 512;              // wave-uniform base; + lane*8 == srow*64+scol
  const int kk0 = (lane >> 4) * 8;

  auto stage = [&](int buf, int kv0) {
    gl2lds16(&kh[(size_t)(kv0 + srow) * HD + kc], &sK[buf][ldsbase]);
    gl2lds16(&vh[(size_t)srow * S + kv0 + kc], &sV[buf][ldsbase]);
  };

  constexpr int NT = S / 64;
  stage(0, 0);
  stage(1, 64);

  for (int ti = 0; ti < NT; ++ti) {
    const int buf = ti % 3;
    // own tile-ti loads done (outstanding at loop top: stage(ti)=2, stage(ti+1)=2)
    if (ti < NT - 1) asm volatile("s_waitcnt vmcnt(2)" ::: "memory");
    else             asm volatile("s_waitcnt vmcnt(0)" ::: "memory");
    __builtin_amdgcn_sched_barrier(0);
    __builtin_amdgcn_s_barrier();  // tile-ti visible everywhere; buf[(ti+2)%3] reader-free

    if (ti + 2 < NT) stage((ti + 2) % 3, (ti + 2) * 64);

    const ushort_t* Kb = &sK[buf][0];
    const ushort_t* Vb = &sV[buf][0];

    // S-tile = Q K^T  (16 q x 64 k per wave), log2 domain
    f32x4 sc[4];
    __builtin_amdgcn_s_setprio(1);
#pragma unroll
    for (int nt = 0; nt < 4; ++nt) {
      sc[nt] = (f32x4){0.f, 0.f, 0.f, 0.f};
      int row = nt * 16 + (lane & 15);
#pragma unroll
      for (int ks = 0; ks < 2; ++ks) {
        int kk = ks * 32 + kk0;
        bf16x8 kf = *(const bf16x8*)&Kb[row * 64 + (kk ^ ((row & 7) << 3))];
        sc[nt] = __builtin_amdgcn_mfma_f32_16x16x32_bf16(qf[ks], kf, sc[nt], 0, 0, 0);
      }
    }
    __builtin_amdgcn_s_setprio(0);

    // fixed-reference softmax: p = 2^s
    float p[4][4];
#pragma unroll
    for (int r = 0; r < 4; ++r) {
      float ps = 0.f;
#pragma unroll
      for (int nt = 0; nt < 4; ++nt) {
        float pv = EXP2(sc[nt][r]);
        p[nt][r] = pv;
        ps += pv;
      }
      lsum[r] += ps;  // per-lane partial; reduced once in epilogue
    }
    // P -> per-wave LDS (swizzled), then read back as A-fragments
    const int prow_base = (lane >> 4) * 4;
#pragma unroll
    for (int nt = 0; nt < 4; ++nt) {
      int col = nt * 16 + (lane & 15);
#pragma unroll
      for (int r = 0; r < 4; ++r) {
        int row = prow_base + r;
        sP[w][row * 64 + (col ^ ((row & 7) << 3))] = f2bf_hw(p[nt][r]);
      }
    }
    bf16x8 pf[2];
    {
      int row = lane & 15;
#pragma unroll
      for (int ks = 0; ks < 2; ++ks) {
        int kk = ks * 32 + kk0;
        pf[ks] = *(const bf16x8*)&sP[w][row * 64 + (kk ^ ((row & 7) << 3))];
      }
    }
    // O += P V   (V^T staged: B-fragment reads contiguous)
    __builtin_amdgcn_s_setprio(1);
#pragma unroll
    for (int nt = 0; nt < 4; ++nt) {
      int row = nt * 16 + (lane & 15);
#pragma unroll
      for (int ks = 0; ks < 2; ++ks) {
        int kk = ks * 32 + kk0;
        bf16x8 vf = *(const bf16x8*)&Vb[row * 64 + (kk ^ ((row & 7) << 3))];
        acc[nt] = __builtin_amdgcn_mfma_f32_16x16x32_bf16(pf[ks], vf, acc[nt], 0, 0, 0);
      }
    }
    __builtin_amdgcn_s_setprio(0);
  }
  // epilogue: reduce per-lane partial sums across the 16-lane row group, write out
  float linv[4];
#pragma unroll
  for (int r = 0; r < 4; ++r) {
    float l = lsum[r];
    l += __shfl_xor(l, 1);
    l += __shfl_xor(l, 2);
    l += __shfl_xor(l, 4);
    l += __shfl_xor(l, 8);
    linv[r] = 1.0f / l;
  }
#pragma unroll
  for (int nt = 0; nt < 4; ++nt)
#pragma unroll
    for (int r = 0; r < 4; ++r) {
      int row = q0 + w * 16 + (lane >> 4) * 4 + r;
      int col = h * HD + nt * 16 + (lane & 15);
      aob[(size_t)row * DMODEL + col] = f2bf_hw(acc[nt][r] * linv[r]);
    }
}

extern "C" void kernel_launch(void* const* d_in, const int* in_sizes, int n_in,
                              void* d_out, int out_size, void* d_ws, size_t ws_size,
                              hipStream_t stream) {
  const float* x = (const float*)d_in[0];
  const float* wqkv = (const float*)d_in[1];
  const float* wo = (const float*)d_in[2];
  float* out = (float*)d_out;
  char* ws = (char*)d_ws;
  const size_t MB = 1024ull * 1024ull;
  ushort_t* xb  = (ushort_t*)(ws);             // x bf16          [4096][1024]  8MB
  ushort_t* wqb = (ushort_t*)(ws + 8 * MB);    // w_qkv bf16      [3072][1024]  6MB
  ushort_t* wob = (ushort_t*)(ws + 14 * MB);   // w_o bf16        [1024][1024]  2MB
  ushort_t* qb  = (ushort_t*)(ws + 16 * MB);   // Q  [16][4096][64]             8MB
  ushort_t* kb  = (ushort_t*)(ws + 24 * MB);   // K  [16][4096][64]             8MB
  ushort_t* vtb = (ushort_t*)(ws + 32 * MB);   // V^T [16][64][4096]            8MB
  ushort_t* aob = (ushort_t*)(ws + 40 * MB);   // attn out bf16 [4096][1024]    8MB

  cvt_f32_bf16<<<(S * DMODEL / 4 + 255) / 256, 256, 0, stream>>>(x, xb, S * DMODEL / 4);
  cvt_f32_bf16<<<(3 * DMODEL * DMODEL / 4 + 255) / 256, 256, 0, stream>>>(wqkv, wqb, 3 * DMODEL * DMODEL / 4);
  cvt_f32_bf16<<<(DMODEL * DMODEL / 4 + 255) / 256, 256, 0, stream>>>(wo, wob, DMODEL * DMODEL / 4);

  dim3 g1(3 * DMODEL / 128, S / 128);
  gemm_bt<1><<<g1, 256, 0, stream>>>(xb, wqb, S, 3 * DMODEL, DMODEL, nullptr, qb, kb, vtb);

  attn_fwd<<<dim3(512), 512, 0, stream>>>(qb, kb, vtb, aob);

  dim3 g2(DMODEL / 64, S / 128);
  gemm_bt_n64<<<g2, 256, 0, stream>>>(aob, wob, S, DMODEL, DMODEL, out);
}